// Round 6
// baseline (4729.865 us; speedup 1.0000x reference)
//
#include <hip/hip_runtime.h>
#include <cstdint>

// FPS: B=8, N=131072, NPOINT=1024.  Exact-index replication of the jax reference.
// R6 = EXACT R2 structure (fastest measured: 2027 us; post path frozen) with ONE
// change: depth-3 software-pipelined polling. Each polling lane keeps 3 loads of
// its slot in flight and checks the oldest (compiler emits vmcnt(2)), sampling
// the slot every ~lambda/3 instead of every ~lambda. Detection ~= V + 0.6*lambda
// instead of V + 1.0-1.5*lambda.
//   R2 structure: update (no-FMA exact fp32) -> per-thread packed key
//   -> 6-level DPP wave max -> lane63 ds_atomic_max into tag-packed LDS u64
//   -> ONE barrier -> tid0 posts LDS value to global slot (relaxed agent store)
//   -> waves poll 16 slots (lanes 0-15, pipelined) -> group16 -> readfirstlane
//   -> winner coords re-read from read-only xyz (L2-hit).
// Packed u64: [t:15][fp32 dist bits:32][(~idx)&0x1FFFF:17] -> unsigned max ==
// (round, dist desc, idx asc) == np.argmax first-max tie-break. Self-tagged
// single-u64 payloads need no fences; parity double-buffer bounds skew to one
// round; 0xAA-poisoned workspace tag never matches a live round tag.

constexpr int kB = 8;
constexpr int kN = 131072;
constexpr int kNpoint = 1024;
constexpr int kBlocksPerBatch = 16;
constexpr int kThreads = 1024;
constexpr int kPPT = 8;
constexpr int kPtsPerBlock = kThreads * kPPT;  // 8192

__device__ __forceinline__ uint64_t u64max(uint64_t a, uint64_t b) {
    return a > b ? a : b;
}

template <int CTRL>
__device__ __forceinline__ uint64_t dpp_u64(uint64_t v) {
    int lo = __builtin_amdgcn_update_dpp(0, (int)(uint32_t)v, CTRL, 0xF, 0xF, false);
    int hi = __builtin_amdgcn_update_dpp(0, (int)(uint32_t)(v >> 32), CTRL, 0xF, 0xF, false);
    return ((uint64_t)(uint32_t)hi << 32) | (uint32_t)lo;
}

// Full-wave max; result valid in lane 63.
__device__ __forceinline__ uint64_t wave_max_to_lane63(uint64_t v) {
    v = u64max(v, dpp_u64<0x111>(v));  // row_shr:1
    v = u64max(v, dpp_u64<0x112>(v));  // row_shr:2
    v = u64max(v, dpp_u64<0x114>(v));  // row_shr:4
    v = u64max(v, dpp_u64<0x118>(v));  // row_shr:8
    v = u64max(v, dpp_u64<0x142>(v));  // row_bcast:15
    v = u64max(v, dpp_u64<0x143>(v));  // row_bcast:31
    return v;
}

// Max over each aligned group of 16 lanes (all lanes of the group get it).
__device__ __forceinline__ uint64_t group16_max(uint64_t v) {
    v = u64max(v, dpp_u64<0xB1>(v));   // quad_perm: xor 1
    v = u64max(v, dpp_u64<0x4E>(v));   // quad_perm: xor 2
    v = u64max(v, dpp_u64<0x141>(v));  // row_half_mirror
    v = u64max(v, dpp_u64<0x140>(v));  // row_mirror
    return v;
}

__global__ __launch_bounds__(kThreads, 4) void fps_kernel(
        const float* __restrict__ xyz, float* __restrict__ out,
        uint64_t* __restrict__ slots) {
    const int b    = blockIdx.x & 7;    // batch (round-robin XCD heuristic)
    const int blk  = blockIdx.x >> 3;   // block within batch, 0..15
    const int tid  = threadIdx.x;
    const int lane = tid & 63;

    const float* __restrict__ base = xyz + (size_t)b * kN * 3;

    float x[kPPT], y[kPPT], z[kPPT], md[kPPT];
#pragma unroll
    for (int j = 0; j < kPPT; ++j) {
        const int p = blk * kPtsPerBlock + j * kThreads + tid;
        x[j] = base[3 * p + 0];
        y[j] = base[3 * p + 1];
        z[j] = base[3 * p + 2];
        md[j] = __builtin_inff();
    }

    __shared__ uint64_t lbest[2];
    if (tid == 0) { lbest[0] = 0; lbest[1] = 0; }

    // First sample is always point 0.
    float cx = base[0], cy = base[1], cz = base[2];
    if (blk == 0 && tid == 0) {
        float* o = out + (size_t)b * kNpoint * 3;
        o[0] = cx; o[1] = cy; o[2] = cz;
    }
    __syncthreads();  // lbest init visible

    for (int t = 1; t < kNpoint; ++t) {
        // --- mindist update + per-thread argmax (exact fp32, no FMA) ---
        float bm = -1.0f;
        int bj = 0;
#pragma unroll
        for (int j = 0; j < kPPT; ++j) {
            const float dx = __fsub_rn(x[j], cx);
            const float dy = __fsub_rn(y[j], cy);
            const float dz = __fsub_rn(z[j], cz);
            const float d  = __fadd_rn(__fadd_rn(__fmul_rn(dx, dx), __fmul_rn(dy, dy)),
                                       __fmul_rn(dz, dz));
            const float m = fminf(md[j], d);
            md[j] = m;
            const bool g = m > bm;        // strict > keeps smallest j among ties
            bj = g ? j : bj;
            bm = g ? m : bm;
        }
        const uint32_t p = (uint32_t)(blk * kPtsPerBlock + bj * kThreads + tid);
        uint64_t pk = ((uint64_t)t << 49) |
                      ((uint64_t)__float_as_uint(bm) << 17) | ((~p) & 0x1FFFFu);

        // --- wave max -> lane 63 -> LDS atomic max (tag-packed, parity dbuf) ---
        pk = wave_max_to_lane63(pk);
        if (lane == 63) {
            __hip_atomic_fetch_max(&lbest[t & 1], pk, __ATOMIC_RELAXED,
                                   __HIP_MEMORY_SCOPE_WORKGROUP);
        }
        __syncthreads();  // the one barrier: block best complete in LDS

        uint64_t* slotbuf = slots + ((size_t)(t & 1) * kB + b) * kBlocksPerBatch;
        if (tid == 0) {
            __hip_atomic_store(&slotbuf[blk], lbest[t & 1], __ATOMIC_RELAXED,
                               __HIP_MEMORY_SCOPE_AGENT);
        }

        // --- depth-3 pipelined spin on the 16 slots (lanes 0-15 only) ---
        uint64_t* sp = &slotbuf[lane & 15];
        const bool act = lane < kBlocksPerBatch;
        uint64_t q0 = 0, q1 = 0, q2 = 0;
        if (act) {
            q0 = __hip_atomic_load(sp, __ATOMIC_RELAXED, __HIP_MEMORY_SCOPE_AGENT);
            q1 = __hip_atomic_load(sp, __ATOMIC_RELAXED, __HIP_MEMORY_SCOPE_AGENT);
            q2 = __hip_atomic_load(sp, __ATOMIC_RELAXED, __HIP_MEMORY_SCOPE_AGENT);
        }
        uint64_t got = 0;
        bool need = act;
        while (__any(need)) {
            if (need) {
                if ((q0 >> 49) == (uint64_t)t) {
                    got = q0;
                    need = false;
                } else {
                    q0 = q1;
                    q1 = q2;
                    q2 = __hip_atomic_load(sp, __ATOMIC_RELAXED, __HIP_MEMORY_SCOPE_AGENT);
                }
            }
        }
        got = group16_max(got);  // lanes 0-15 hold the batch winner

        const uint32_t blo = (uint32_t)__builtin_amdgcn_readfirstlane((int)(uint32_t)got);
        const uint32_t widx = 131071u - (blo & 0x1FFFFu);
        cx = base[3 * (size_t)widx + 0];
        cy = base[3 * (size_t)widx + 1];
        cz = base[3 * (size_t)widx + 2];
        if (blk == 0 && tid == 0) {
            float* o = out + ((size_t)b * kNpoint + t) * 3;
            o[0] = cx; o[1] = cy; o[2] = cz;
        }
    }
}

extern "C" void kernel_launch(void* const* d_in, const int* in_sizes, int n_in,
                              void* d_out, int out_size, void* d_ws, size_t ws_size,
                              hipStream_t stream) {
    const float* xyz = (const float*)d_in[0];
    float* out = (float*)d_out;
    uint64_t* slots = (uint64_t*)d_ws;  // 2 * 8 * 16 u64 = 2 KiB used
    fps_kernel<<<dim3(kB * kBlocksPerBatch), dim3(kThreads), 0, stream>>>(xyz, out, slots);
}

// Round 7
// 2188.166 us; speedup vs baseline: 2.1616x; 2.1616x over previous
//
#include <hip/hip_runtime.h>
#include <cstdint>

// FPS: B=8, N=131072, NPOINT=1024.  Exact-index replication of the jax reference.
// R7 = EXACT R2 structure (fastest mode: 2027 us; post/poll structure frozen)
// with ONE change: each slot padded to its own 128B cache line (stride 16 u64).
// Theory: agent-scope poll loads from 16 lanes to the same line serialize at
// the coherence point (~2400 cyc effective poll quantum, which also explains
// R4/R6's identical +2.5-quantum regressions). 16 distinct lines -> parallel
// service -> quantum drops to single-load latency (~600-900 cyc).
//   R2 structure: update (no-FMA exact fp32) -> per-thread packed key
//   -> 6-level DPP wave max -> lane63 ds_atomic_max into tag-packed LDS u64
//   -> ONE barrier -> tid0 posts LDS value to global slot (relaxed agent store)
//   -> all waves spin on 16 slots (lanes 0-15, one load + check per iter)
//   -> 4-level DPP group16, readfirstlane, winner coords re-read from xyz (L2).
// Packed u64: [t:15][fp32 dist bits:32][(~idx)&0x1FFFF:17] -> unsigned max ==
// (round, dist desc, idx asc) == np.argmax first-max tie-break. Self-tagged
// single-u64 payloads need no fences; parity double-buffer bounds skew to one
// round; 0xAA-poisoned workspace tag never matches a live round tag.

constexpr int kB = 8;
constexpr int kN = 131072;
constexpr int kNpoint = 1024;
constexpr int kBlocksPerBatch = 16;
constexpr int kThreads = 1024;
constexpr int kPPT = 8;
constexpr int kPtsPerBlock = kThreads * kPPT;  // 8192
constexpr int kSlotStride = 16;                // u64s: one slot per 128B line

__device__ __forceinline__ uint64_t u64max(uint64_t a, uint64_t b) {
    return a > b ? a : b;
}

template <int CTRL>
__device__ __forceinline__ uint64_t dpp_u64(uint64_t v) {
    int lo = __builtin_amdgcn_update_dpp(0, (int)(uint32_t)v, CTRL, 0xF, 0xF, false);
    int hi = __builtin_amdgcn_update_dpp(0, (int)(uint32_t)(v >> 32), CTRL, 0xF, 0xF, false);
    return ((uint64_t)(uint32_t)hi << 32) | (uint32_t)lo;
}

// Full-wave max; result valid in lane 63.
__device__ __forceinline__ uint64_t wave_max_to_lane63(uint64_t v) {
    v = u64max(v, dpp_u64<0x111>(v));  // row_shr:1
    v = u64max(v, dpp_u64<0x112>(v));  // row_shr:2
    v = u64max(v, dpp_u64<0x114>(v));  // row_shr:4
    v = u64max(v, dpp_u64<0x118>(v));  // row_shr:8
    v = u64max(v, dpp_u64<0x142>(v));  // row_bcast:15
    v = u64max(v, dpp_u64<0x143>(v));  // row_bcast:31
    return v;
}

// Max over each aligned group of 16 lanes (all lanes of the group get it).
__device__ __forceinline__ uint64_t group16_max(uint64_t v) {
    v = u64max(v, dpp_u64<0xB1>(v));   // quad_perm: xor 1
    v = u64max(v, dpp_u64<0x4E>(v));   // quad_perm: xor 2
    v = u64max(v, dpp_u64<0x141>(v));  // row_half_mirror
    v = u64max(v, dpp_u64<0x140>(v));  // row_mirror
    return v;
}

__global__ __launch_bounds__(kThreads, 4) void fps_kernel(
        const float* __restrict__ xyz, float* __restrict__ out,
        uint64_t* __restrict__ slots) {
    const int b    = blockIdx.x & 7;    // batch: 16 blocks of a batch -> one XCD
    const int blk  = blockIdx.x >> 3;   // block within batch, 0..15
    const int tid  = threadIdx.x;
    const int lane = tid & 63;

    const float* __restrict__ base = xyz + (size_t)b * kN * 3;

    float x[kPPT], y[kPPT], z[kPPT], md[kPPT];
#pragma unroll
    for (int j = 0; j < kPPT; ++j) {
        const int p = blk * kPtsPerBlock + j * kThreads + tid;
        x[j] = base[3 * p + 0];
        y[j] = base[3 * p + 1];
        z[j] = base[3 * p + 2];
        md[j] = __builtin_inff();
    }

    __shared__ uint64_t lbest[2];
    if (tid == 0) { lbest[0] = 0; lbest[1] = 0; }

    // First sample is always point 0.
    float cx = base[0], cy = base[1], cz = base[2];
    if (blk == 0 && tid == 0) {
        float* o = out + (size_t)b * kNpoint * 3;
        o[0] = cx; o[1] = cy; o[2] = cz;
    }
    __syncthreads();  // lbest init visible

    for (int t = 1; t < kNpoint; ++t) {
        // --- mindist update + per-thread argmax (exact fp32, no FMA) ---
        float bm = -1.0f;
        int bj = 0;
#pragma unroll
        for (int j = 0; j < kPPT; ++j) {
            const float dx = __fsub_rn(x[j], cx);
            const float dy = __fsub_rn(y[j], cy);
            const float dz = __fsub_rn(z[j], cz);
            const float d  = __fadd_rn(__fadd_rn(__fmul_rn(dx, dx), __fmul_rn(dy, dy)),
                                       __fmul_rn(dz, dz));
            const float m = fminf(md[j], d);
            md[j] = m;
            const bool g = m > bm;        // strict > keeps smallest j among ties
            bj = g ? j : bj;
            bm = g ? m : bm;
        }
        const uint32_t p = (uint32_t)(blk * kPtsPerBlock + bj * kThreads + tid);
        uint64_t pk = ((uint64_t)t << 49) |
                      ((uint64_t)__float_as_uint(bm) << 17) | ((~p) & 0x1FFFFu);

        // --- wave max -> lane 63 -> LDS atomic max (tag-packed, parity dbuf) ---
        pk = wave_max_to_lane63(pk);
        if (lane == 63) {
            __hip_atomic_fetch_max(&lbest[t & 1], pk, __ATOMIC_RELAXED,
                                   __HIP_MEMORY_SCOPE_WORKGROUP);
        }
        __syncthreads();  // the one barrier: block best complete in LDS

        uint64_t* slotbuf =
            slots + ((size_t)(t & 1) * kB + b) * kBlocksPerBatch * kSlotStride;
        if (tid == 0) {
            __hip_atomic_store(&slotbuf[blk * kSlotStride], lbest[t & 1],
                               __ATOMIC_RELAXED, __HIP_MEMORY_SCOPE_AGENT);
        }

        // --- every wave spins on the 16 padded slots (lanes 0-15 only) ---
        uint64_t got = 0;
        bool need = lane < kBlocksPerBatch;
        while (__any(need)) {
            if (need) {
                uint64_t sv = __hip_atomic_load(&slotbuf[lane * kSlotStride],
                                                __ATOMIC_RELAXED,
                                                __HIP_MEMORY_SCOPE_AGENT);
                if ((sv >> 49) == (uint64_t)t) { got = sv; need = false; }
            }
        }
        got = group16_max(got);  // lanes 0-15 hold the batch winner

        const uint32_t blo = (uint32_t)__builtin_amdgcn_readfirstlane((int)(uint32_t)got);
        const uint32_t widx = 131071u - (blo & 0x1FFFFu);
        cx = base[3 * (size_t)widx + 0];
        cy = base[3 * (size_t)widx + 1];
        cz = base[3 * (size_t)widx + 2];
        if (blk == 0 && tid == 0) {
            float* o = out + ((size_t)b * kNpoint + t) * 3;
            o[0] = cx; o[1] = cy; o[2] = cz;
        }
    }
}

extern "C" void kernel_launch(void* const* d_in, const int* in_sizes, int n_in,
                              void* d_out, int out_size, void* d_ws, size_t ws_size,
                              hipStream_t stream) {
    const float* xyz = (const float*)d_in[0];
    float* out = (float*)d_out;
    uint64_t* slots = (uint64_t*)d_ws;  // 2 * 8 * 16 slots * 128B = 32 KiB used
    fps_kernel<<<dim3(kB * kBlocksPerBatch), dim3(kThreads), 0, stream>>>(xyz, out, slots);
}